// Round 8
// baseline (380.791 us; speedup 1.0000x reference)
//
#include <hip/hip_runtime.h>
#include <math.h>

// Problem constants
#define BB 16
#define NN 1024
#define FF 128
#define NCG 64
#define NCONV 3
#define CAP 8

typedef double f64x4 __attribute__((ext_vector_type(4)));

// ---- output layout (floats) ----
static const size_t O_M     = 0;
static const size_t O_MN    = (size_t)BB*NN*NCG;              // 1048576
static const size_t O_H     = O_MN  + (size_t)BB*NN*NCG;      // 2097152
static const size_t O_HH    = O_H   + (size_t)BB*NN*FF;       // 4194304
static const size_t O_ADJ   = O_HH  + (size_t)BB*NCG*FF;      // 4325376
static const size_t O_CGXYZ = O_ADJ + (size_t)BB*NN*NN;       // 21102592
static const size_t O_CGADJ = O_CGXYZ + (size_t)BB*NCG*3;     // 21105664
static const size_t O_KN    = O_CGADJ + (size_t)BB*NCG*NCG;   // 21171200

// f64 scratch aliased into adj output region (written last). adj = 8388608 doubles.
static const size_t S_H64   = 0;         // [B*N*F] = 2M doubles
static const size_t S_T64   = 2097152;   // [B*N*F]
static const size_t S_C64   = 4194304;   // [B*N*F]
static const size_t S_LM64  = 0;         // aliases h64 (dead by then)
static const size_t S_HPF   = 6291456;   // 16 x [B*NCG*F] floats = 1M doubles
static const size_t S_CGP   = 7340032;   // 32 x [B*NCG*3] doubles
static const size_t S_NBR   = 7438336;   // B*N*CAP ints
static const size_t S_W64   = 7503872;   // 122880 doubles
// end 7626752 < 8388608 OK

// W64 internal offsets (doubles)
static const size_t WO_CGW1 = 98304;
static const size_t WO_CGW2 = 114688;
static const int    W64_N   = 122880;

// ---- ws layout (doubles) ----
static const size_t W_COLS = 0;                                // [B*NCG]
static const size_t W_CG64 = (size_t)BB*NCG;                   // [B*NCG*3]
static const size_t W_CNT  = W_CG64 + (size_t)BB*NCG*3;        // B*N ints

// ---------------- fused init: cnt/colsum zero, cgadj, W cvt, emb ----------------
__global__ void k_init(const int* __restrict__ atoms, const float* __restrict__ emb,
                       const float* __restrict__ uW1, const float* __restrict__ uW2,
                       const float* __restrict__ cgW1, const float* __restrict__ cgW2,
                       double* __restrict__ W64, float* __restrict__ cgadj,
                       int* __restrict__ cnt, double* __restrict__ colsum,
                       double* __restrict__ h64) {
    int i = blockIdx.x * blockDim.x + threadIdx.x;   // grid 2048*256 = 524288
    if (i < BB*NN) cnt[i] = 0;
    if (i < BB*NCG) colsum[i] = 0.0;
    if (i < W64_N) {
        float v;
        if (i < 98304) {
            int l = i >> 15, r = i & 32767;
            v = (r < 16384) ? uW1[l*16384 + r] : uW2[l*16384 + (r & 16383)];
        } else if (i < 114688) v = cgW1[i - 98304];
        else                   v = cgW2[i - 114688];
        W64[i] = (double)v;
    }
    if (i < BB*NCG*NCG) {
        int r = (i / NCG) % NCG, cjj = i % NCG;
        cgadj[i] = (r == cjj) ? 0.f : 1.f;
    }
    if (i < BB*NN*(FF/4)) {
        int n = i / (FF/4), f4 = i % (FF/4);
        int a = atoms[n];
        const float4 v = *reinterpret_cast<const float4*>(&emb[(size_t)a*FF + f4*4]);
        double* hp = &h64[(size_t)n*FF + f4*4];
        hp[0] = (double)v.x; hp[1] = (double)v.y; hp[2] = (double)v.z; hp[3] = (double)v.w;
    }
}

__global__ void k_build_nbr(const int* __restrict__ bonds, int nb, int* cnt, int* nbr) {
    int i = blockIdx.x * blockDim.x + threadIdx.x;
    if (i >= nb) return;
    int b = bonds[i*3+0], s = bonds[i*3+1], t = bonds[i*3+2];
    int ns = b*NN + s, nt = b*NN + t;
    int p = atomicAdd(&cnt[ns], 1);
    if (p < CAP) nbr[(size_t)ns*CAP + p] = nt;
    int q = atomicAdd(&cnt[nt], 1);
    if (q < CAP) nbr[(size_t)nt*CAP + q] = ns;
}

// ---------------- plain f64 MFMA GEMM (proven, round 7) ----------------
// 64-row x 64-col blocks, 4 waves, v_mfma_f64_16x16x4.
template<int COUTT, bool TANH>
__global__ __launch_bounds__(256) void k_gemm_mfma(const double* __restrict__ in,
                                                   const double* __restrict__ W,
                                                   const float* __restrict__ bias,
                                                   double* __restrict__ out) {
    constexpr int K = 128, KC = 32;
    constexpr int CT2 = COUTT/2;
    __shared__ double As[64*34];
    __shared__ double Ws[KC*66];
    const int tid = threadIdx.x;
    const int col0 = blockIdx.y * 64;
    const int C02 = col0 >> 1;
    const size_t row0 = (size_t)blockIdx.x * 64;
    const double2* in2 = reinterpret_cast<const double2*>(in + row0*K);
    const double2* Wg2 = reinterpret_cast<const double2*>(W);
    double2* As2 = reinterpret_cast<double2*>(As);
    double2* Ws2 = reinterpret_cast<double2*>(Ws);

    double2 pA[4], pW[4];
    #pragma unroll
    for (int i = 0; i < 4; ++i) { int q = tid + i*256; pA[i] = in2[(q>>4)*64 + (q&15)]; }
    #pragma unroll
    for (int i = 0; i < 4; ++i) { int q = tid + i*256; pW[i] = Wg2[(q>>5)*CT2 + C02 + (q&31)]; }

    const int lane = tid & 63;
    const int wv = tid >> 6;
    const int m = lane & 15, kq = lane >> 4;
    const int arow = (wv*16 + m)*34 + kq;

    f64x4 acc[4];
    #pragma unroll
    for (int ct = 0; ct < 4; ++ct) acc[ct] = (f64x4){0.0, 0.0, 0.0, 0.0};

    for (int kc = 0; kc < K; kc += KC) {
        __syncthreads();
        #pragma unroll
        for (int i = 0; i < 4; ++i) { int q = tid + i*256; As2[(q>>4)*17 + (q&15)] = pA[i]; }
        #pragma unroll
        for (int i = 0; i < 4; ++i) { int q = tid + i*256; Ws2[(q>>5)*33 + (q&31)] = pW[i]; }
        if (kc + KC < K) {
            const int kn = kc + KC, kn2 = kn >> 1;
            #pragma unroll
            for (int i = 0; i < 4; ++i) { int q = tid + i*256; pA[i] = in2[(q>>4)*64 + kn2 + (q&15)]; }
            #pragma unroll
            for (int i = 0; i < 4; ++i) { int q = tid + i*256; pW[i] = Wg2[(kn + (q>>5))*CT2 + C02 + (q&31)]; }
        }
        __syncthreads();
        #pragma unroll
        for (int kk = 0; kk < KC; kk += 4) {
            double a = As[arow + kk];
            const double* wrow = Ws + (kk + kq)*66 + m;
            #pragma unroll
            for (int ct = 0; ct < 4; ++ct) {
                double b = wrow[ct*16];
                acc[ct] = __builtin_amdgcn_mfma_f64_16x16x4f64(a, b, acc[ct], 0, 0, 0);
            }
        }
    }

    const int orow = wv*16 + kq*4;
    #pragma unroll
    for (int ct = 0; ct < 4; ++ct) {
        int c = col0 + ct*16 + m;
        double bv = (double)bias[c];
        #pragma unroll
        for (int i = 0; i < 4; ++i) {
            double v = acc[ct][i] + bv;
            if (TANH) v = tanh(v);
            out[(row0 + orow + i)*COUTT + c] = v;
        }
    }
}

// ---------------- fused gather + f64 MFMA GEMM (COUT=128, tanh) ----------------
// 32 rows x 128 cols, 4 waves (2 row-halves x 2 col-halves). Staging computes
// h' = h + invdeg * sum_nbr ch[nbr] (block-local rows; ch fully written before),
// writes h' to global (+ optional f32 copy) and to LDS, then MFMA over full K.
template<bool GATHER, bool WRITE_F32>
__global__ __launch_bounds__(256) void k_gemm_fg(const double* __restrict__ in,
        const double* __restrict__ ch, const int* __restrict__ nbr,
        const int* __restrict__ cnt, const double* __restrict__ W,
        const float* __restrict__ bias, double* __restrict__ hupd,
        float* __restrict__ hf32, double* __restrict__ out) {
    constexpr int K = 128, KC = 32, AST = 130, WST = 130;
    __shared__ double As[32*AST];   // 33.3 KB (full K staged once)
    __shared__ double Ws[KC*WST];   // 33.3 KB
    const int tid = threadIdx.x;
    const size_t row0 = (size_t)blockIdx.x * 32;
    const double2* Wg2 = reinterpret_cast<const double2*>(W);

    // prefetch W chunk 0
    double2 pW[8];
    #pragma unroll
    for (int i = 0; i < 8; ++i) { int q = tid + i*256; pW[i] = Wg2[q]; }

    // fused gather staging: thread (srow, skg) handles 16 doubles
    {
        const int srow = tid >> 3, skg = tid & 7;
        const size_t grow = row0 + srow;
        double2 v[8];
        const double2* hp = reinterpret_cast<const double2*>(in + grow*K) + skg*8;
        #pragma unroll
        for (int i = 0; i < 8; ++i) v[i] = hp[i];
        if (GATHER) {
            int c = cnt[grow];
            double w = c > 0 ? 1.0/(double)c : 0.0;
            for (int q = 0; q < c; ++q) {
                int nb2 = nbr[grow*CAP + q];
                const double2* cp = reinterpret_cast<const double2*>(ch + (size_t)nb2*K) + skg*8;
                #pragma unroll
                for (int i = 0; i < 8; ++i) { double2 t = cp[i]; v[i].x += w*t.x; v[i].y += w*t.y; }
            }
            double2* hg = reinterpret_cast<double2*>(hupd + grow*K) + skg*8;
            #pragma unroll
            for (int i = 0; i < 8; ++i) hg[i] = v[i];
        }
        if (WRITE_F32) {
            float4* fp = reinterpret_cast<float4*>(hf32 + grow*K) + skg*4;
            #pragma unroll
            for (int i = 0; i < 4; ++i) {
                float4 o;
                o.x = (float)v[2*i].x;   o.y = (float)v[2*i].y;
                o.z = (float)v[2*i+1].x; o.w = (float)v[2*i+1].y;
                fp[i] = o;
            }
        }
        double2* ap = reinterpret_cast<double2*>(As + srow*AST) + skg*8;
        #pragma unroll
        for (int i = 0; i < 8; ++i) ap[i] = v[i];
    }

    const int lane = tid & 63, wv = tid >> 6;
    const int wr = wv & 1, wc = wv >> 1;
    const int m = lane & 15, kq = lane >> 4;
    const int abase = (wr*16 + m)*AST;

    f64x4 acc[4];
    #pragma unroll
    for (int ct = 0; ct < 4; ++ct) acc[ct] = (f64x4){0.0, 0.0, 0.0, 0.0};

    for (int kc = 0; kc < K; kc += KC) {
        __syncthreads();   // A ready (first) / prev Ws reads done
        #pragma unroll
        for (int i = 0; i < 8; ++i) {
            int q = tid + i*256;
            reinterpret_cast<double2*>(Ws + (q>>6)*WST)[q & 63] = pW[i];
        }
        if (kc + KC < K) {
            #pragma unroll
            for (int i = 0; i < 8; ++i) {
                int q = tid + i*256;
                pW[i] = Wg2[(kc + KC + (q>>6))*64 + (q & 63)];
            }
        }
        __syncthreads();
        #pragma unroll
        for (int kk = 0; kk < KC; kk += 4) {
            double a = As[abase + kc + kk + kq];
            const double* wrow = Ws + (kk + kq)*WST + wc*64 + m;
            #pragma unroll
            for (int ct = 0; ct < 4; ++ct) {
                double b = wrow[ct*16];
                acc[ct] = __builtin_amdgcn_mfma_f64_16x16x4f64(a, b, acc[ct], 0, 0, 0);
            }
        }
    }

    const int orow = wr*16 + kq*4;
    #pragma unroll
    for (int ct = 0; ct < 4; ++ct) {
        int c = wc*64 + ct*16 + m;
        double bv = (double)bias[c];
        #pragma unroll
        for (int i = 0; i < 4; ++i)
            out[(row0 + orow + i)*K + c] = tanh(acc[ct][i] + bv);
    }
}

// ---------------- gumbel softmax (f64, in-place logits->M) + atomic colsum ----------------
__global__ void k_softmax64(double* __restrict__ lm, const float* __restrict__ gum,
                            const float* __restrict__ tau_p, float* __restrict__ M_out,
                            double* __restrict__ colsum) {
    int row = blockIdx.x * 4 + threadIdx.x / 64;
    int lane = threadIdx.x & 63;
    double tau = (double)(*tau_p);
    double u = (double)gum[(size_t)row*NCG + lane];
    double g = -log(-log(u));
    double v = (lm[(size_t)row*NCG + lane] + g) / tau;
    double m = v;
    #pragma unroll
    for (int off = 32; off; off >>= 1) m = fmax(m, __shfl_xor(m, off));
    double e = exp(v - m);
    double s = e;
    #pragma unroll
    for (int off = 32; off; off >>= 1) s += __shfl_xor(s, off);
    double mv = e / s;
    lm[(size_t)row*NCG + lane] = mv;
    M_out[(size_t)row*NCG + lane] = (float)mv;
    atomicAdd(&colsum[(row >> 10) * NCG + lane], mv);
}

__global__ void k_mnorm_out(const double* __restrict__ M, const double* __restrict__ colsum,
                            float* __restrict__ Mn) {
    size_t i = (size_t)blockIdx.x * blockDim.x + threadIdx.x;
    if (i >= (size_t)BB*NN*NCG) return;
    size_t b = i >> 16;
    int j = (int)(i & 63);
    Mn[i] = (float)(M[i] / colsum[b*NCG + j]);
}

// ---------------- H partials (f32): 16 chunks of 64 rows ----------------
__global__ __launch_bounds__(256) void k_Hpart32(const float* __restrict__ Mn,
                                                 const float* __restrict__ h,
                                                 float* __restrict__ Hp) {
    __shared__ float Ms[32*NCG];
    __shared__ float hs[32*FF];
    const int b = blockIdx.x, ch = blockIdx.y;
    const int tid = threadIdx.x;
    const int tc = tid % 32, tr = tid / 32;
    const float4* M4 = reinterpret_cast<const float4*>(Mn + (size_t)b*NN*NCG);
    const float4* h4 = reinterpret_cast<const float4*>(h + (size_t)b*NN*FF);
    float4* Ms4 = reinterpret_cast<float4*>(Ms);
    float4* hs4 = reinterpret_cast<float4*>(hs);
    const float2* Ms2 = reinterpret_cast<const float2*>(Ms);
    const float2* hs2 = reinterpret_cast<const float2*>(hs);

    float acc[8][4];
    #pragma unroll
    for (int i = 0; i < 8; ++i)
        #pragma unroll
        for (int j = 0; j < 4; ++j) acc[i][j] = 0.f;

    for (int s = 0; s < 2; ++s) {
        const int n0 = ch*64 + s*32;
        __syncthreads();
        #pragma unroll
        for (int i = 0; i < 2; ++i) Ms4[tid + i*256] = M4[n0*16 + tid + i*256];
        #pragma unroll
        for (int i = 0; i < 4; ++i) hs4[tid + i*256] = h4[n0*32 + tid + i*256];
        __syncthreads();
        for (int n = 0; n < 32; ++n) {
            float2 hv0 = hs2[n*64 + tc];
            float2 hv1 = hs2[n*64 + 32 + tc];
            float2 m0 = Ms2[n*32 + tr];
            float2 m1 = Ms2[n*32 + 8 + tr];
            float2 m2 = Ms2[n*32 + 16 + tr];
            float2 m3 = Ms2[n*32 + 24 + tr];
            float mj[8] = {m0.x, m0.y, m1.x, m1.y, m2.x, m2.y, m3.x, m3.y};
            #pragma unroll
            for (int jj = 0; jj < 8; ++jj) {
                acc[jj][0] += mj[jj]*hv0.x; acc[jj][1] += mj[jj]*hv0.y;
                acc[jj][2] += mj[jj]*hv1.x; acc[jj][3] += mj[jj]*hv1.y;
            }
        }
    }
    float* Ho = Hp + ((size_t)ch*BB + b) * NCG * FF;
    #pragma unroll
    for (int gj = 0; gj < 4; ++gj)
        #pragma unroll
        for (int pj = 0; pj < 2; ++pj) {
            int j = tr*2 + gj*16 + pj;
            int jj = gj*2 + pj;
            float2 o0; o0.x = acc[jj][0]; o0.y = acc[jj][1];
            float2 o1; o1.x = acc[jj][2]; o1.y = acc[jj][3];
            float2* op = reinterpret_cast<float2*>(Ho + (size_t)j*FF);
            op[tc] = o0; op[32 + tc] = o1;
        }
}

__global__ void k_Hfin32(const float* __restrict__ Hp, float* __restrict__ H) {
    int idx = blockIdx.x * blockDim.x + threadIdx.x;
    if (idx >= BB*NCG*FF) return;
    int b = idx / (NCG*FF);
    int r = idx % (NCG*FF);
    float s = 0.f;
    #pragma unroll
    for (int c = 0; c < 16; ++c) s += Hp[((size_t)c*BB + b)*NCG*FF + r];
    H[idx] = s;
}

// ---------------- cg partials (f64, feeds knbrs): 32 chunks of 32 rows ----------------
__global__ __launch_bounds__(192) void k_cgpart(const double* __restrict__ M,
                                                const float* __restrict__ xyz,
                                                double* __restrict__ cgp) {
    __shared__ double Ms[32*NCG];
    __shared__ double xs[32*3];
    const int b = blockIdx.x, ch = blockIdx.y;
    const int tid = threadIdx.x;
    const int j = tid / 3, d = tid % 3;
    const int n0 = ch*32;
    const double2* M2 = reinterpret_cast<const double2*>(M + (size_t)b*NN*NCG);
    double2* Ms2 = reinterpret_cast<double2*>(Ms);
    const float* xb = xyz + (size_t)b*NN*3;
    for (int q = tid; q < 1024; q += 192) Ms2[q] = M2[n0*32 + q];
    for (int q = tid; q < 96; q += 192) xs[q] = (double)xb[n0*3 + q];
    __syncthreads();
    double acc = 0.0;
    #pragma unroll 8
    for (int n = 0; n < 32; ++n) acc += Ms[n*NCG + j] * xs[n*3 + d];
    cgp[((size_t)ch*BB + b)*192 + tid] = acc;
}

__global__ void k_cgfin(const double* __restrict__ cgp, const double* __restrict__ colsum,
                        double* __restrict__ cg64, float* __restrict__ cg) {
    int idx = blockIdx.x * blockDim.x + threadIdx.x;
    if (idx >= BB*NCG*3) return;
    int b = idx / (NCG*3);
    int r = idx % (NCG*3);
    int j = r / 3;
    double s = 0.0;
    #pragma unroll
    for (int c = 0; c < 32; ++c) s += cgp[((size_t)c*BB + b)*192 + r];
    double v = s / colsum[b*NCG + j];
    cg64[idx] = v;
    cg[idx] = (float)v;
}

// ---------------- knbrs: rank-count argsort over squared distances ----------------
__global__ __launch_bounds__(1024) void k_knbrs(const double* __restrict__ cg,
                                                float* __restrict__ kn) {
    __shared__ double cs[NCG*3];
    const int b = blockIdx.x;
    const int tid = threadIdx.x;
    const int i = blockIdx.y * 16 + tid / 64;
    const int j = tid & 63;
    if (tid < NCG*3) cs[tid] = cg[(size_t)b*NCG*3 + tid];
    __syncthreads();
    double xi = cs[i*3+0], yi = cs[i*3+1], zi = cs[i*3+2];
    double dxj = xi - cs[j*3+0], dyj = yi - cs[j*3+1], dzj = zi - cs[j*3+2];
    double d2j = dxj*dxj + dyj*dyj + dzj*dzj;
    int rank = 0;
    for (int k = 0; k < NCG; ++k) {
        double dx = xi - cs[k*3+0], dy = yi - cs[k*3+1], dz = zi - cs[k*3+2];
        double d2k = dx*dx + dy*dy + dz*dz;
        rank += (d2k < d2j) || (d2k == d2j && k < j);
    }
    kn[(size_t)b*NCG*NCG + (size_t)i*NCG + rank] = (float)j;
}

// ---------------- adj (written LAST; region doubles as f64 scratch) ----------------
__global__ void k_zero_adj(float4* adj4, long n4) {
    long i = (long)blockIdx.x * blockDim.x + threadIdx.x;
    long stride = (long)gridDim.x * blockDim.x;
    float4 z; z.x = z.y = z.z = z.w = 0.f;
    for (; i < n4; i += stride) adj4[i] = z;
}

__global__ void k_bonds_adj(const int* __restrict__ bonds, int nb, float* adj) {
    int i = blockIdx.x * blockDim.x + threadIdx.x;
    if (i >= nb) return;
    int b = bonds[i*3+0], s = bonds[i*3+1], t = bonds[i*3+2];
    size_t base = (size_t)b * NN * NN;
    adj[base + (size_t)s*NN + t] = 1.f;
    adj[base + (size_t)t*NN + s] = 1.f;
}

extern "C" void kernel_launch(void* const* d_in, const int* in_sizes, int n_in,
                              void* d_out, int out_size, void* d_ws, size_t ws_size,
                              hipStream_t stream) {
    const int*   atoms  = (const int*)  d_in[0];
    const float* xyz    = (const float*)d_in[1];
    const int*   bonds  = (const int*)  d_in[2];
    const float* tau    = (const float*)d_in[3];
    const float* gum    = (const float*)d_in[4];
    const float* emb    = (const float*)d_in[5];
    const float* uW1    = (const float*)d_in[6];
    const float* ub1    = (const float*)d_in[7];
    const float* uW2    = (const float*)d_in[8];
    const float* ub2    = (const float*)d_in[9];
    const float* cgW1   = (const float*)d_in[10];
    const float* cgb1   = (const float*)d_in[11];
    const float* cgW2   = (const float*)d_in[12];
    const float* cgb2   = (const float*)d_in[13];

    float* out = (float*)d_out;
    float* o_M   = out + O_M;
    float* o_Mn  = out + O_MN;
    float* o_h   = out + O_H;
    float* o_H   = out + O_HH;
    float* o_adj = out + O_ADJ;
    float* o_cg  = out + O_CGXYZ;
    float* o_ca  = out + O_CGADJ;
    float* o_kn  = out + O_KN;

    double* scr   = (double*)o_adj;
    double* h64   = scr + S_H64;
    double* t64   = scr + S_T64;
    double* c64   = scr + S_C64;
    double* lm64  = scr + S_LM64;     // aliases h64 (h64 dead when written)
    float*  Hpf   = (float*)(scr + S_HPF);
    double* cgp   = scr + S_CGP;
    int*    nbr   = (int*)(scr + S_NBR);
    double* W64   = scr + S_W64;

    double* wsd    = (double*)d_ws;
    double* colsum = wsd + W_COLS;
    double* cg64   = wsd + W_CG64;
    int*    cnt    = (int*)(wsd + W_CNT);

    const int nb = in_sizes[2] / 3;

    hipLaunchKernelGGL(k_init, dim3(2048), dim3(256), 0, stream,
                       atoms, emb, uW1, uW2, cgW1, cgW2, W64, o_ca, cnt, colsum, h64);
    hipLaunchKernelGGL(k_build_nbr, dim3((nb+255)/256), dim3(256), 0, stream,
                       bonds, nb, cnt, nbr);

    // layer 0: no gather
    hipLaunchKernelGGL((k_gemm_mfma<128,true>), dim3(256,2), dim3(256), 0, stream,
                       h64, W64, ub1, t64);
    hipLaunchKernelGGL((k_gemm_mfma<128,false>), dim3(256,2), dim3(256), 0, stream,
                       t64, W64 + 16384, ub2, c64);
    // layer 1: gather(c64) fused into staging
    hipLaunchKernelGGL((k_gemm_fg<true,false>), dim3(512), dim3(256), 0, stream,
                       h64, c64, nbr, cnt, W64 + 32768, ub1 + FF, h64, o_h, t64);
    hipLaunchKernelGGL((k_gemm_mfma<128,false>), dim3(256,2), dim3(256), 0, stream,
                       t64, W64 + 32768 + 16384, ub2 + FF, c64);
    // layer 2
    hipLaunchKernelGGL((k_gemm_fg<true,false>), dim3(512), dim3(256), 0, stream,
                       h64, c64, nbr, cnt, W64 + 65536, ub1 + 2*FF, h64, o_h, t64);
    hipLaunchKernelGGL((k_gemm_mfma<128,false>), dim3(256,2), dim3(256), 0, stream,
                       t64, W64 + 65536 + 16384, ub2 + 2*FF, c64);
    // head: final gather fused, writes o_h (f32)
    hipLaunchKernelGGL((k_gemm_fg<true,true>), dim3(512), dim3(256), 0, stream,
                       h64, c64, nbr, cnt, W64 + WO_CGW1, cgb1, h64, o_h, t64);
    hipLaunchKernelGGL((k_gemm_mfma<64,false>), dim3(256,1), dim3(256), 0, stream,
                       t64, W64 + WO_CGW2, cgb2, lm64);

    hipLaunchKernelGGL(k_softmax64, dim3(4096), dim3(256), 0, stream,
                       lm64, gum, tau, o_M, colsum);
    hipLaunchKernelGGL(k_mnorm_out, dim3(4096), dim3(256), 0, stream, lm64, colsum, o_Mn);
    hipLaunchKernelGGL(k_Hpart32, dim3(BB, 16), dim3(256), 0, stream, o_Mn, o_h, Hpf);
    hipLaunchKernelGGL(k_Hfin32, dim3(512), dim3(256), 0, stream, Hpf, o_H);
    hipLaunchKernelGGL(k_cgpart, dim3(BB, 32), dim3(192), 0, stream, lm64, xyz, cgp);
    hipLaunchKernelGGL(k_cgfin, dim3(12), dim3(256), 0, stream, cgp, colsum, cg64, o_cg);
    hipLaunchKernelGGL(k_knbrs, dim3(BB, 4), dim3(1024), 0, stream, cg64, o_kn);

    // adj LAST: its region was scratch until here
    hipLaunchKernelGGL(k_zero_adj, dim3(4096), dim3(256), 0, stream,
                       (float4*)o_adj, (long)BB*NN*NN/4);
    hipLaunchKernelGGL(k_bonds_adj, dim3((nb+255)/256), dim3(256), 0, stream,
                       bonds, nb, o_adj);
}

// Round 9
// 361.152 us; speedup vs baseline: 1.0544x; 1.0544x over previous
//
#include <hip/hip_runtime.h>
#include <math.h>

// Problem constants
#define BB 16
#define NN 1024
#define FF 128
#define NCG 64
#define NCONV 3
#define CAP 8

typedef double f64x4 __attribute__((ext_vector_type(4)));

// ---- output layout (floats) ----
static const size_t O_M     = 0;
static const size_t O_MN    = (size_t)BB*NN*NCG;              // 1048576
static const size_t O_H     = O_MN  + (size_t)BB*NN*NCG;      // 2097152
static const size_t O_HH    = O_H   + (size_t)BB*NN*FF;       // 4194304
static const size_t O_ADJ   = O_HH  + (size_t)BB*NCG*FF;      // 4325376
static const size_t O_CGXYZ = O_ADJ + (size_t)BB*NN*NN;       // 21102592
static const size_t O_CGADJ = O_CGXYZ + (size_t)BB*NCG*3;     // 21105664
static const size_t O_KN    = O_CGADJ + (size_t)BB*NCG*NCG;   // 21171200

// f64 scratch aliased into adj output region (written last). adj = 8388608 doubles.
static const size_t S_H64   = 0;         // [B*N*F] = 2M doubles
static const size_t S_T64   = 2097152;   // [B*N*F]
static const size_t S_C64   = 4194304;   // [B*N*F]
static const size_t S_LM64  = 0;         // aliases h64 (dead by then)
static const size_t S_HPF   = 6291456;   // 16 x [B*NCG*F] floats = 1M doubles
static const size_t S_CGP   = 7340032;   // 32 x [B*NCG*3] doubles = 98304
static const size_t S_W64   = 7503872;   // 122880 doubles
// end 7626752 < 8388608 OK

// W64 internal offsets (doubles)
static const size_t WO_CGW1 = 98304;
static const size_t WO_CGW2 = 114688;
static const int    W64_N   = 122880;

// ---- ws layout (doubles; ws is ~255MB, verified via poison WRITE_SIZE) ----
static const size_t W_COLS = 0;                                // colsum [B*NCG]
static const size_t W_CNT  = (size_t)BB*NCG;                   // cnt: B*N ints
static const size_t W_NBR  = W_CNT + (size_t)BB*NN/2;          // nbr: B*N*CAP ints

// ---------------- fused init: cnt/colsum zero, cgadj, W cvt, emb ----------------
__global__ void k_init(const int* __restrict__ atoms, const float* __restrict__ emb,
                       const float* __restrict__ uW1, const float* __restrict__ uW2,
                       const float* __restrict__ cgW1, const float* __restrict__ cgW2,
                       double* __restrict__ W64, float* __restrict__ cgadj,
                       int* __restrict__ cnt, double* __restrict__ colsum,
                       double* __restrict__ h64) {
    int i = blockIdx.x * blockDim.x + threadIdx.x;   // grid 2048*256 = 524288
    if (i < BB*NN) cnt[i] = 0;
    if (i < BB*NCG) colsum[i] = 0.0;
    if (i < W64_N) {
        float v;
        if (i < 98304) {
            int l = i >> 15, r = i & 32767;
            v = (r < 16384) ? uW1[l*16384 + r] : uW2[l*16384 + (r & 16383)];
        } else if (i < 114688) v = cgW1[i - 98304];
        else                   v = cgW2[i - 114688];
        W64[i] = (double)v;
    }
    if (i < BB*NCG*NCG) {
        int r = (i / NCG) % NCG, cjj = i % NCG;
        cgadj[i] = (r == cjj) ? 0.f : 1.f;
    }
    if (i < BB*NN*(FF/4)) {
        int n = i / (FF/4), f4 = i % (FF/4);
        int a = atoms[n];
        const float4 v = *reinterpret_cast<const float4*>(&emb[(size_t)a*FF + f4*4]);
        double* hp = &h64[(size_t)n*FF + f4*4];
        hp[0] = (double)v.x; hp[1] = (double)v.y; hp[2] = (double)v.z; hp[3] = (double)v.w;
    }
}

__global__ void k_build_nbr(const int* __restrict__ bonds, int nb, int* cnt, int* nbr) {
    int i = blockIdx.x * blockDim.x + threadIdx.x;
    if (i >= nb) return;
    int b = bonds[i*3+0], s = bonds[i*3+1], t = bonds[i*3+2];
    int ns = b*NN + s, nt = b*NN + t;
    int p = atomicAdd(&cnt[ns], 1);
    if (p < CAP) nbr[(size_t)ns*CAP + p] = nt;
    int q = atomicAdd(&cnt[nt], 1);
    if (q < CAP) nbr[(size_t)nt*CAP + q] = ns;
}

// ---------------- plain f64 MFMA GEMM (proven, round 7) ----------------
// 64-row x 64-col blocks, 4 waves, v_mfma_f64_16x16x4.
template<int COUTT, bool TANH>
__global__ __launch_bounds__(256) void k_gemm_mfma(const double* __restrict__ in,
                                                   const double* __restrict__ W,
                                                   const float* __restrict__ bias,
                                                   double* __restrict__ out) {
    constexpr int K = 128, KC = 32;
    constexpr int CT2 = COUTT/2;
    __shared__ double As[64*34];
    __shared__ double Ws[KC*66];
    const int tid = threadIdx.x;
    const int col0 = blockIdx.y * 64;
    const int C02 = col0 >> 1;
    const size_t row0 = (size_t)blockIdx.x * 64;
    const double2* in2 = reinterpret_cast<const double2*>(in + row0*K);
    const double2* Wg2 = reinterpret_cast<const double2*>(W);
    double2* As2 = reinterpret_cast<double2*>(As);
    double2* Ws2 = reinterpret_cast<double2*>(Ws);

    double2 pA[4], pW[4];
    #pragma unroll
    for (int i = 0; i < 4; ++i) { int q = tid + i*256; pA[i] = in2[(q>>4)*64 + (q&15)]; }
    #pragma unroll
    for (int i = 0; i < 4; ++i) { int q = tid + i*256; pW[i] = Wg2[(q>>5)*CT2 + C02 + (q&31)]; }

    const int lane = tid & 63;
    const int wv = tid >> 6;
    const int m = lane & 15, kq = lane >> 4;
    const int arow = (wv*16 + m)*34 + kq;

    f64x4 acc[4];
    #pragma unroll
    for (int ct = 0; ct < 4; ++ct) acc[ct] = (f64x4){0.0, 0.0, 0.0, 0.0};

    for (int kc = 0; kc < K; kc += KC) {
        __syncthreads();
        #pragma unroll
        for (int i = 0; i < 4; ++i) { int q = tid + i*256; As2[(q>>4)*17 + (q&15)] = pA[i]; }
        #pragma unroll
        for (int i = 0; i < 4; ++i) { int q = tid + i*256; Ws2[(q>>5)*33 + (q&31)] = pW[i]; }
        if (kc + KC < K) {
            const int kn = kc + KC, kn2 = kn >> 1;
            #pragma unroll
            for (int i = 0; i < 4; ++i) { int q = tid + i*256; pA[i] = in2[(q>>4)*64 + kn2 + (q&15)]; }
            #pragma unroll
            for (int i = 0; i < 4; ++i) { int q = tid + i*256; pW[i] = Wg2[(kn + (q>>5))*CT2 + C02 + (q&31)]; }
        }
        __syncthreads();
        #pragma unroll
        for (int kk = 0; kk < KC; kk += 4) {
            double a = As[arow + kk];
            const double* wrow = Ws + (kk + kq)*66 + m;
            #pragma unroll
            for (int ct = 0; ct < 4; ++ct) {
                double b = wrow[ct*16];
                acc[ct] = __builtin_amdgcn_mfma_f64_16x16x4f64(a, b, acc[ct], 0, 0, 0);
            }
        }
    }

    const int orow = wv*16 + kq*4;
    #pragma unroll
    for (int ct = 0; ct < 4; ++ct) {
        int c = col0 + ct*16 + m;
        double bv = (double)bias[c];
        #pragma unroll
        for (int i = 0; i < 4; ++i) {
            double v = acc[ct][i] + bv;
            if (TANH) v = tanh(v);
            out[(row0 + orow + i)*COUTT + c] = v;
        }
    }
}

// ---------------- gather: h[node,:] += (1/deg) * sum_nbr ch[nbr,:] ----------------
template<bool WRITE_F32>
__global__ void k_gather(const double* __restrict__ ch, const int* __restrict__ nbr,
                         const int* __restrict__ cnt, double* __restrict__ h,
                         float* __restrict__ hout) {
    int idx = blockIdx.x * blockDim.x + threadIdx.x;
    if (idx >= BB*NN*(FF/4)) return;
    int node = idx >> 5, f4 = idx & 31;
    int c = cnt[node];
    double2 s0; s0.x = 0.0; s0.y = 0.0;
    double2 s1 = s0;
    for (int q = 0; q < c; ++q) {
        int nb = nbr[(size_t)node*CAP + q];
        const double2* cp = reinterpret_cast<const double2*>(ch + (size_t)nb*FF + f4*4);
        double2 a = cp[0], b2 = cp[1];
        s0.x += a.x; s0.y += a.y; s1.x += b2.x; s1.y += b2.y;
    }
    double w = c > 0 ? 1.0/(double)c : 0.0;
    double2* hp = reinterpret_cast<double2*>(h + (size_t)node*FF + f4*4);
    double2 h0 = hp[0], h1 = hp[1];
    h0.x += s0.x*w; h0.y += s0.y*w; h1.x += s1.x*w; h1.y += s1.y*w;
    hp[0] = h0; hp[1] = h1;
    if (WRITE_F32) {
        float4 o; o.x = (float)h0.x; o.y = (float)h0.y; o.z = (float)h1.x; o.w = (float)h1.y;
        *reinterpret_cast<float4*>(&hout[(size_t)node*FF + f4*4]) = o;
    }
}

// ---------------- gumbel softmax (f64, in-place logits->M) + block-reduced colsum ----------------
__global__ __launch_bounds__(256) void k_softmax64(double* __restrict__ lm,
                            const float* __restrict__ gum,
                            const float* __restrict__ tau_p, float* __restrict__ M_out,
                            double* __restrict__ colsum) {
    __shared__ double red[256];
    int row = blockIdx.x * 4 + threadIdx.x / 64;   // 4 rows per block, same batch
    int lane = threadIdx.x & 63;
    double tau = (double)(*tau_p);
    double u = (double)gum[(size_t)row*NCG + lane];
    double g = -log(-log(u));
    double v = (lm[(size_t)row*NCG + lane] + g) / tau;
    double m = v;
    #pragma unroll
    for (int off = 32; off; off >>= 1) m = fmax(m, __shfl_xor(m, off));
    double e = exp(v - m);
    double s = e;
    #pragma unroll
    for (int off = 32; off; off >>= 1) s += __shfl_xor(s, off);
    double mv = e / s;
    lm[(size_t)row*NCG + lane] = mv;
    M_out[(size_t)row*NCG + lane] = (float)mv;
    red[threadIdx.x] = mv;
    __syncthreads();
    if (threadIdx.x < 64) {
        int b = row >> 10;
        atomicAdd(&colsum[b*NCG + lane],
                  red[lane] + red[64+lane] + red[128+lane] + red[192+lane]);
    }
}

__global__ void k_mnorm_out(const double* __restrict__ M, const double* __restrict__ colsum,
                            float* __restrict__ Mn) {
    size_t i = (size_t)blockIdx.x * blockDim.x + threadIdx.x;
    if (i >= (size_t)BB*NN*NCG) return;
    size_t b = i >> 16;
    int j = (int)(i & 63);
    Mn[i] = (float)(M[i] / colsum[b*NCG + j]);
}

// ---------------- H partials (f32): 16 chunks of 64 rows ----------------
__global__ __launch_bounds__(256) void k_Hpart32(const float* __restrict__ Mn,
                                                 const float* __restrict__ h,
                                                 float* __restrict__ Hp) {
    __shared__ float Ms[32*NCG];
    __shared__ float hs[32*FF];
    const int b = blockIdx.x, ch = blockIdx.y;
    const int tid = threadIdx.x;
    const int tc = tid % 32, tr = tid / 32;
    const float4* M4 = reinterpret_cast<const float4*>(Mn + (size_t)b*NN*NCG);
    const float4* h4 = reinterpret_cast<const float4*>(h + (size_t)b*NN*FF);
    float4* Ms4 = reinterpret_cast<float4*>(Ms);
    float4* hs4 = reinterpret_cast<float4*>(hs);
    const float2* Ms2 = reinterpret_cast<const float2*>(Ms);
    const float2* hs2 = reinterpret_cast<const float2*>(hs);

    float acc[8][4];
    #pragma unroll
    for (int i = 0; i < 8; ++i)
        #pragma unroll
        for (int j = 0; j < 4; ++j) acc[i][j] = 0.f;

    for (int s = 0; s < 2; ++s) {
        const int n0 = ch*64 + s*32;
        __syncthreads();
        #pragma unroll
        for (int i = 0; i < 2; ++i) Ms4[tid + i*256] = M4[n0*16 + tid + i*256];
        #pragma unroll
        for (int i = 0; i < 4; ++i) hs4[tid + i*256] = h4[n0*32 + tid + i*256];
        __syncthreads();
        for (int n = 0; n < 32; ++n) {
            float2 hv0 = hs2[n*64 + tc];
            float2 hv1 = hs2[n*64 + 32 + tc];
            float2 m0 = Ms2[n*32 + tr];
            float2 m1 = Ms2[n*32 + 8 + tr];
            float2 m2 = Ms2[n*32 + 16 + tr];
            float2 m3 = Ms2[n*32 + 24 + tr];
            float mj[8] = {m0.x, m0.y, m1.x, m1.y, m2.x, m2.y, m3.x, m3.y};
            #pragma unroll
            for (int jj = 0; jj < 8; ++jj) {
                acc[jj][0] += mj[jj]*hv0.x; acc[jj][1] += mj[jj]*hv0.y;
                acc[jj][2] += mj[jj]*hv1.x; acc[jj][3] += mj[jj]*hv1.y;
            }
        }
    }
    float* Ho = Hp + ((size_t)ch*BB + b) * NCG * FF;
    #pragma unroll
    for (int gj = 0; gj < 4; ++gj)
        #pragma unroll
        for (int pj = 0; pj < 2; ++pj) {
            int j = tr*2 + gj*16 + pj;
            int jj = gj*2 + pj;
            float2 o0; o0.x = acc[jj][0]; o0.y = acc[jj][1];
            float2 o1; o1.x = acc[jj][2]; o1.y = acc[jj][3];
            float2* op = reinterpret_cast<float2*>(Ho + (size_t)j*FF);
            op[tc] = o0; op[32 + tc] = o1;
        }
}

__global__ void k_Hfin32(const float* __restrict__ Hp, float* __restrict__ H) {
    int idx = blockIdx.x * blockDim.x + threadIdx.x;
    if (idx >= BB*NCG*FF) return;
    int b = idx / (NCG*FF);
    int r = idx % (NCG*FF);
    float s = 0.f;
    #pragma unroll
    for (int c = 0; c < 16; ++c) s += Hp[((size_t)c*BB + b)*NCG*FF + r];
    H[idx] = s;
}

// ---------------- cg partials (f64, feeds knbrs): 32 chunks of 32 rows ----------------
__global__ __launch_bounds__(192) void k_cgpart(const double* __restrict__ M,
                                                const float* __restrict__ xyz,
                                                double* __restrict__ cgp) {
    __shared__ double Ms[32*NCG];
    __shared__ double xs[32*3];
    const int b = blockIdx.x, ch = blockIdx.y;
    const int tid = threadIdx.x;
    const int j = tid / 3, d = tid % 3;
    const int n0 = ch*32;
    const double2* M2 = reinterpret_cast<const double2*>(M + (size_t)b*NN*NCG);
    double2* Ms2 = reinterpret_cast<double2*>(Ms);
    const float* xb = xyz + (size_t)b*NN*3;
    for (int q = tid; q < 1024; q += 192) Ms2[q] = M2[n0*32 + q];
    for (int q = tid; q < 96; q += 192) xs[q] = (double)xb[n0*3 + q];
    __syncthreads();
    double acc = 0.0;
    #pragma unroll 8
    for (int n = 0; n < 32; ++n) acc += Ms[n*NCG + j] * xs[n*3 + d];
    cgp[((size_t)ch*BB + b)*192 + tid] = acc;
}

// ---------------- knbrs (absorbs cgfin): reduce cgp, write o_cg, rank-count ----------------
__global__ __launch_bounds__(1024) void k_knbrs(const double* __restrict__ cgp,
                                                const double* __restrict__ colsum,
                                                float* __restrict__ o_cg,
                                                float* __restrict__ kn) {
    __shared__ double cs[NCG*3];
    const int b = blockIdx.x;
    const int tid = threadIdx.x;
    if (tid < NCG*3) {
        double s = 0.0;
        #pragma unroll
        for (int c = 0; c < 32; ++c) s += cgp[((size_t)c*BB + b)*192 + tid];
        double v = s / colsum[b*NCG + tid/3];
        cs[tid] = v;
        if (blockIdx.y == 0) o_cg[(size_t)b*192 + tid] = (float)v;
    }
    __syncthreads();
    const int i = blockIdx.y * 16 + tid / 64;
    const int j = tid & 63;
    double xi = cs[i*3+0], yi = cs[i*3+1], zi = cs[i*3+2];
    double dxj = xi - cs[j*3+0], dyj = yi - cs[j*3+1], dzj = zi - cs[j*3+2];
    double d2j = dxj*dxj + dyj*dyj + dzj*dzj;
    int rank = 0;
    for (int k = 0; k < NCG; ++k) {
        double dx = xi - cs[k*3+0], dy = yi - cs[k*3+1], dz = zi - cs[k*3+2];
        double d2k = dx*dx + dy*dy + dz*dz;
        rank += (d2k < d2j) || (d2k == d2j && k < j);
    }
    kn[(size_t)b*NCG*NCG + (size_t)i*NCG + rank] = (float)j;
}

// ---------------- adj: single-pass write from nbr lists (written LAST) ----------------
// block = one row (b,s); thread t writes cols 4t..4t+3.
__global__ __launch_bounds__(256) void k_adj(const int* __restrict__ cnt,
                                             const int* __restrict__ nbr,
                                             float4* __restrict__ adj4) {
    const int node = blockIdx.x;           // b*NN + s
    const int t = threadIdx.x;
    const int col0 = t*4;
    int c = cnt[node];
    if (c > CAP) c = CAP;
    float4 v; v.x = v.y = v.z = v.w = 0.f;
    for (int q = 0; q < c; ++q) {
        int dst = nbr[(size_t)node*CAP + q] & (NN-1);   // t index within batch
        int d = dst - col0;
        if (d == 0) v.x = 1.f;
        else if (d == 1) v.y = 1.f;
        else if (d == 2) v.z = 1.f;
        else if (d == 3) v.w = 1.f;
    }
    adj4[(size_t)node*256 + t] = v;
}

extern "C" void kernel_launch(void* const* d_in, const int* in_sizes, int n_in,
                              void* d_out, int out_size, void* d_ws, size_t ws_size,
                              hipStream_t stream) {
    const int*   atoms  = (const int*)  d_in[0];
    const float* xyz    = (const float*)d_in[1];
    const int*   bonds  = (const int*)  d_in[2];
    const float* tau    = (const float*)d_in[3];
    const float* gum    = (const float*)d_in[4];
    const float* emb    = (const float*)d_in[5];
    const float* uW1    = (const float*)d_in[6];
    const float* ub1    = (const float*)d_in[7];
    const float* uW2    = (const float*)d_in[8];
    const float* ub2    = (const float*)d_in[9];
    const float* cgW1   = (const float*)d_in[10];
    const float* cgb1   = (const float*)d_in[11];
    const float* cgW2   = (const float*)d_in[12];
    const float* cgb2   = (const float*)d_in[13];

    float* out = (float*)d_out;
    float* o_M   = out + O_M;
    float* o_Mn  = out + O_MN;
    float* o_h   = out + O_H;
    float* o_H   = out + O_HH;
    float* o_adj = out + O_ADJ;
    float* o_cg  = out + O_CGXYZ;
    float* o_ca  = out + O_CGADJ;
    float* o_kn  = out + O_KN;

    double* scr   = (double*)o_adj;
    double* h64   = scr + S_H64;
    double* t64   = scr + S_T64;
    double* c64   = scr + S_C64;
    double* lm64  = scr + S_LM64;     // aliases h64 (h64 dead when written)
    float*  Hpf   = (float*)(scr + S_HPF);
    double* cgp   = scr + S_CGP;
    double* W64   = scr + S_W64;

    double* wsd    = (double*)d_ws;
    double* colsum = wsd + W_COLS;
    int*    cnt    = (int*)(wsd + W_CNT);
    int*    nbr    = (int*)(wsd + W_NBR);

    const int nb = in_sizes[2] / 3;

    hipLaunchKernelGGL(k_init, dim3(2048), dim3(256), 0, stream,
                       atoms, emb, uW1, uW2, cgW1, cgW2, W64, o_ca, cnt, colsum, h64);
    hipLaunchKernelGGL(k_build_nbr, dim3((nb+255)/256), dim3(256), 0, stream,
                       bonds, nb, cnt, nbr);

    for (int l = 0; l < NCONV; ++l) {
        hipLaunchKernelGGL((k_gemm_mfma<128,true>), dim3(256,2), dim3(256), 0, stream,
                           h64, W64 + (size_t)l*32768, ub1 + (size_t)l*FF, t64);
        hipLaunchKernelGGL((k_gemm_mfma<128,false>), dim3(256,2), dim3(256), 0, stream,
                           t64, W64 + (size_t)l*32768 + 16384, ub2 + (size_t)l*FF, c64);
        if (l < NCONV-1)
            hipLaunchKernelGGL((k_gather<false>), dim3(2048), dim3(256), 0, stream,
                               c64, nbr, cnt, h64, o_h);
        else
            hipLaunchKernelGGL((k_gather<true>), dim3(2048), dim3(256), 0, stream,
                               c64, nbr, cnt, h64, o_h);
    }

    hipLaunchKernelGGL((k_gemm_mfma<128,true>), dim3(256,2), dim3(256), 0, stream,
                       h64, W64 + WO_CGW1, cgb1, t64);
    hipLaunchKernelGGL((k_gemm_mfma<64,false>), dim3(256,1), dim3(256), 0, stream,
                       t64, W64 + WO_CGW2, cgb2, lm64);

    hipLaunchKernelGGL(k_softmax64, dim3(4096), dim3(256), 0, stream,
                       lm64, gum, tau, o_M, colsum);
    hipLaunchKernelGGL(k_mnorm_out, dim3(4096), dim3(256), 0, stream, lm64, colsum, o_Mn);
    hipLaunchKernelGGL(k_Hpart32, dim3(BB, 16), dim3(256), 0, stream, o_Mn, o_h, Hpf);
    hipLaunchKernelGGL(k_Hfin32, dim3(512), dim3(256), 0, stream, Hpf, o_H);
    hipLaunchKernelGGL(k_cgpart, dim3(BB, 32), dim3(192), 0, stream, lm64, xyz, cgp);
    hipLaunchKernelGGL(k_knbrs, dim3(BB, 4), dim3(1024), 0, stream,
                       cgp, colsum, o_cg, o_kn);

    // adj LAST (single pass): its region was f64 scratch until here
    hipLaunchKernelGGL(k_adj, dim3(BB*NN), dim3(256), 0, stream,
                       cnt, nbr, (float4*)o_adj);
}